// Round 17
// baseline (44.008 us; speedup 1.0000x reference)
//
#include <hip/hip_runtime.h>

#define DET 1024
#define CLIPV 20.0f

// DPP lane permutation (quad_perm imm8, 0x140 row_mirror, 0x141 row_half_mirror)
template<int CTRL>
__device__ __forceinline__ float dppx(float v) {
    int i = __float_as_int(v);
    int r = __builtin_amdgcn_update_dpp(i, i, CTRL, 0xF, 0xF, false);
    return __int_as_float(r);
}

struct Coef {
    float g10[6], g11[6], g20[6], g21[6];
    bool  j1[6];   // true iff t1 is the j=1 candidate (per lane, per phase)
};

// One ACS step at (wave-local) phase K. Verified butterfly algebra (rounds 3-16):
// lane L holds M_tau[rotr6(L, tau%6)]; partner = L^(1<<K).
template<int K, bool DEC>
__device__ __forceinline__ void acs_step(float lxv, float lyv, float& m, unsigned& acc,
                                         const Coef& cf) {
    float C1 = __builtin_fmaf(cf.g10[K], lxv, cf.g11[K] * lyv);
    float C2 = __builtin_fmaf(cf.g20[K], lxv, cf.g21[K] * lyv);
    float e1, e2;
    if constexpr (K == 0)      { e1 = m; e2 = dppx<0xB1>(m); }
    else if constexpr (K == 1) { e1 = m; e2 = dppx<0x4E>(m); }
    else if constexpr (K == 2) { e1 = m; e2 = dppx<0x141>(dppx<0x1B>(m)); }
    else if constexpr (K == 3) { e1 = m; e2 = dppx<0x140>(dppx<0x141>(m)); }
    else {
        int a1 = __float_as_int(m), a2;
        if constexpr (K == 4)
            asm("v_mov_b32 %1, %0\n\ts_nop 1\n\tv_permlane16_swap_b32 %0, %1\n\ts_nop 1"
                : "+v"(a1), "=&v"(a2));
        else
            asm("v_mov_b32 %1, %0\n\ts_nop 1\n\tv_permlane32_swap_b32 %0, %1\n\ts_nop 1"
                : "+v"(a1), "=&v"(a2));
        e1 = __int_as_float(a1); e2 = __int_as_float(a2);
    }
    float t1 = e1 + C1, t2 = e2 + C2;
    float mn = fminf(t1, t2);
    if constexpr (DEC) {
        // d = argmin j (tie -> j=0): tj0 = the j=0 candidate; d = (mn < tj0)
        float tj0 = cf.j1[K] ? t2 : t1;
        acc = acc + acc + (mn < tj0 ? 1u : 0u);
    }
    m = __builtin_amdgcn_fmed3f(mn, -CLIPV, CLIPV);
}

// Pipelined 16-step block: issue NEXT block's 8 ds_read_b128 into vn, then
// compute 16 steps on the pre-loaded vc (LDS latency hidden under compute).
template<int P, bool DEC>
__device__ __forceinline__ void sub16p(const float2* lq, int& lidx,
                                       float4 (&vc)[8], float4 (&vn)[8],
                                       float& m, unsigned& acc, const Coef& cf) {
    const float4* bp = reinterpret_cast<const float4*>(lq + lidx);  // 16-aligned lidx
    #pragma unroll
    for (int j = 0; j < 8; ++j) vn[j] = bp[j];
    #define SPAIR(JH)                                                          \
        acs_step<(P + 2 * (JH)) % 6, DEC>(vc[JH].x, vc[JH].y, m, acc, cf);     \
        acs_step<(P + 2 * (JH) + 1) % 6, DEC>(vc[JH].z, vc[JH].w, m, acc, cf);
    SPAIR(0) SPAIR(1) SPAIR(2) SPAIR(3) SPAIR(4) SPAIR(5) SPAIR(6) SPAIR(7)
    #undef SPAIR
    lidx = (lidx + 16) & (DET - 1);
}

// 8 traceback steps from prefetched qword buffer (verified rounds 5-16).
#define TBSTEPS(QARR, TBTOP, RT) do {                                          \
    _Pragma("unroll")                                                          \
    for (int j = 0; j < 8; ++j) {                                              \
        const int t = (TBTOP) - j;                                             \
        int r = (RT) - (j % 6); if (r < 0) r += 6;                             \
        int Lx = ((st << r) | (st >> (6 - r))) & 63;                           \
        int bit = (int)((QARR[j] >> Lx) & 1ull);                               \
        unsigned ob = (~(unsigned)st) & 1u;                                    \
        int ii = t - 1024;                                                     \
        acc |= ob << (ii & 31);                                                \
        if ((ii & 31) == 0) { bitsl[cw][L][(ii >> 5) & 3] = acc; acc = 0; }    \
        st = ((st << 1) | bit) & 63;                                           \
    }                                                                          \
} while (0)

// 512 blocks x 512 threads (8 waves = 4 waves/SIMD at 2 blocks/CU). One batch
// per block. Periodic input + W=96 exact coalescence (verified r13/r15/r16;
// W=48 refuted r14). Wave w: 96 warmup + 128 decode steps for chunk
// t in [1024+128w, 1024+128(w+1)); (96+128) % 6 == 2 -> traceback rtop = 2.
// No barriers between forward, own-window transpose, and own-chunk traceback.
__global__ __launch_bounds__(512, 4) void cva_kernel(const float* __restrict__ x,
                                                     float* __restrict__ out) {
    const int bidx = blockIdx.x;
    const int tid  = threadIdx.x;
    const int L    = tid & 63;
    const int w    = tid >> 6;

    __shared__ float2 lx[DET];                  // 8 KB LLR pairs
    __shared__ unsigned decw[32 * 64];          // 8 KB per-lane decision words
    __shared__ unsigned long long masks[1024];  // 8 KB t-indexed decision masks
    __shared__ unsigned bitsl[8][64][4];        // 8 KB speculative bit strings
    __shared__ unsigned char gmap[8][64];       // chunk state maps

    const float2* __restrict__ xrow =
        reinterpret_cast<const float2*>(x + (size_t)bidx * 2048);
    for (int i = tid; i < DET; i += 512) lx[i] = xrow[i];
    __syncthreads();

    // ---- forward ACS: wave w decodes t in [1024+128w, 1024+128(w+1)) ----
    {
        // probe permlane swap orientation once (per-lane constant; verified r5-r16)
        bool P16, P32;
        {
            int p1 = L, p2;
            asm("v_mov_b32 %1, %0\n\ts_nop 1\n\tv_permlane16_swap_b32 %0, %1\n\ts_nop 1"
                : "+v"(p1), "=&v"(p2));
            P16 = (p1 == (L ^ 16));
            int q1 = L, q2;
            asm("v_mov_b32 %1, %0\n\ts_nop 1\n\tv_permlane32_swap_b32 %0, %1\n\ts_nop 1"
                : "+v"(q1), "=&v"(q2));
            P32 = (q1 == (L ^ 32));
        }
        Coef cf;
        #pragma unroll
        for (int k = 0; k < 6; ++k) {
            int r = (k + 1) % 6;
            int sn = ((L >> r) | (L << (6 - r))) & 63;   // rotr6(L, r)
            int b = (sn >> 5) & 1;
            int q0 = (sn << 1) & 63;
            int q1b = q0 | 1;
            int qo = b ? q1b : q0;                       // own candidate  (j=b)
            int qp = b ? q0 : q1b;                       // partner's      (j=1-b)
            float fo0 = (float)((b ^ (qo >> 5) ^ (qo >> 4) ^ (qo >> 3) ^ qo) & 1);
            float fo1 = (float)((b ^ (qo >> 4) ^ (qo >> 3) ^ (qo >> 1) ^ qo) & 1);
            float fp0 = (float)((b ^ (qp >> 5) ^ (qp >> 4) ^ (qp >> 3) ^ qp) & 1);
            float fp1 = (float)((b ^ (qp >> 4) ^ (qp >> 3) ^ (qp >> 1) ^ qp) & 1);
            bool P = (k == 4) ? P16 : ((k == 5) ? P32 : false);
            cf.g10[k] = P ? fp0 : fo0; cf.g11[k] = P ? fp1 : fo1;   // coeffs for e1
            cf.g20[k] = P ? fo0 : fp0; cf.g21[k] = P ? fo1 : fp1;   // coeffs for e2
            cf.j1[k] = ((b != 0) != P);                  // t1 is j=1 cand iff b^P
        }

        float m = 0.0f;
        unsigned acc = 0;
        float4 bufA[8], bufB[8];
        int lidx = (928 + 128 * w) & (DET - 1);          // warmup start = t0 - 96
        {                                                 // prologue: load block 0
            const float4* bp = reinterpret_cast<const float4*>(lx + lidx);
            #pragma unroll
            for (int j = 0; j < 8; ++j) bufA[j] = bp[j];
            lidx = (lidx + 16) & (DET - 1);
        }
        // warmup: 6 sub16 = 96 steps, phases cycle {0,4,2}, buffers alternate
        {
            sub16p<0, false>(lx, lidx, bufA, bufB, m, acc, cf);
            sub16p<4, false>(lx, lidx, bufB, bufA, m, acc, cf);
            sub16p<2, false>(lx, lidx, bufA, bufB, m, acc, cf);
            sub16p<0, false>(lx, lidx, bufB, bufA, m, acc, cf);
            sub16p<4, false>(lx, lidx, bufA, bufB, m, acc, cf);
            sub16p<2, false>(lx, lidx, bufB, bufA, m, acc, cf);
        }
        // decode: 4 windows of 32 steps; window word -> LDS (keeps regs lean)
        #pragma unroll
        for (int wd = 0; wd < 4; ++wd) {
            const int ph = wd % 3;                       // window start phase (2*wd)%6
            if (ph == 0) {
                sub16p<0, true>(lx, lidx, bufA, bufB, m, acc, cf);
                sub16p<4, true>(lx, lidx, bufB, bufA, m, acc, cf);
            } else if (ph == 1) {
                sub16p<2, true>(lx, lidx, bufA, bufB, m, acc, cf);
                sub16p<0, true>(lx, lidx, bufB, bufA, m, acc, cf);
            } else {
                sub16p<4, true>(lx, lidx, bufA, bufB, m, acc, cf);
                sub16p<2, true>(lx, lidx, bufB, bufA, m, acc, cf);
            }
            decw[(4 * w + wd) * 64 + L] = acc;           // window index 4w+wd
        }
    }

    // ---- own-window bit-transpose (same-wave LDS readback, no barrier) ----
    for (int n = 0; n < 4; ++n) {
        unsigned W = decw[(4 * w + n) * 64 + L];
        unsigned mlo = 0, mhi = 0;
        #pragma unroll
        for (int i = 0; i < 32; ++i) {
            unsigned long long bal = __ballot(((W >> (31 - i)) & 1u) != 0);
            bool sel = (L == i);                         // lane i keeps t = 1024+(4w+n)*32+i
            mlo = sel ? (unsigned)bal : mlo;
            mhi = sel ? (unsigned)(bal >> 32) : mhi;
        }
        if (L < 32)
            masks[(4 * w + n) * 32 + L] = ((unsigned long long)mhi << 32) | mlo;
    }

    // ---- speculative traceback: chunk cw = w reads ONLY its own masks slice ----
    {
        const int cw = w;
        int st = L;                                      // speculative top-boundary state
        unsigned acc = 0;
        int tb0 = 1024 + 128 * cw + 127;
        int rtop = 2;                                    // (223+1)%6, same for all chunks
        unsigned long long qa[8], qb[8];
        #pragma unroll
        for (int j = 0; j < 8; ++j) qa[j] = masks[tb0 - 1024 - j];
        for (int blk = 0; blk < 16; blk += 2) {
            const int tb1 = tb0 - 8;
            #pragma unroll
            for (int j = 0; j < 8; ++j) qb[j] = masks[tb1 - 1024 - j];
            TBSTEPS(qa, tb0, rtop);
            const int tb2 = tb0 - 16;
            if (blk + 2 < 16) {
                #pragma unroll
                for (int j = 0; j < 8; ++j) qa[j] = masks[tb2 - 1024 - j];
            }
            int rt1 = rtop - 2; if (rt1 < 0) rt1 += 6;
            TBSTEPS(qb, tb1, rt1);
            rtop = rt1 - 2; if (rtop < 0) rtop += 6;
            tb0 -= 16;
        }
        gmap[cw][L] = (unsigned char)st;
    }
    __syncthreads();                                     // the ONLY tail barrier

    // ---- redundant per-thread compose (pass A = rep2 via periodicity, then
    //      emitting-pass entries, all statically unrolled) + direct output ----
    {
        int s = 0;                                       // state at t=3072 boundary
        s = gmap[7][s]; s = gmap[6][s]; s = gmap[5][s]; s = gmap[4][s];
        s = gmap[3][s]; s = gmap[2][s]; s = gmap[1][s]; s = gmap[0][s];  // pass A
        int e7 = s; s = gmap[7][s];
        int e6 = s; s = gmap[6][s];
        int e5 = s; s = gmap[5][s];
        int e4 = s; s = gmap[4][s];
        int e3 = s; s = gmap[3][s];
        int e2 = s; s = gmap[2][s];
        int e1 = s; s = gmap[1][s];
        int e0 = s;
        float* orow = out + (size_t)bidx * DET;
        const int word = (tid & 127) >> 5, bit = tid & 31;
        const int b = tid >> 7;                          // 0..3
        // element i = tid: chunk = b, entry selected statically
        int elo = (b & 1) ? e1 : e0;
        int ehi = (b & 1) ? e3 : e2;
        int ee  = (b & 2) ? ehi : elo;
        orow[tid] = (float)((bitsl[b][ee][word] >> bit) & 1u);
        // element i = 512 + tid: chunk = 4 + b
        int flo = (b & 1) ? e5 : e4;
        int fhi = (b & 1) ? e7 : e6;
        int ff  = (b & 2) ? fhi : flo;
        orow[tid + 512] = (float)((bitsl[4 + b][ff][word] >> bit) & 1u);
    }
}

extern "C" void kernel_launch(void* const* d_in, const int* in_sizes, int n_in,
                              void* d_out, int out_size, void* d_ws, size_t ws_size,
                              hipStream_t stream) {
    const float* x = (const float*)d_in[0];
    float* out = (float*)d_out;
    (void)in_sizes; (void)n_in; (void)d_ws; (void)ws_size; (void)out_size;
    hipLaunchKernelGGL(cva_kernel, dim3(512), dim3(512), 0, stream, x, out);
}

// Round 18
// 41.992 us; speedup vs baseline: 1.0480x; 1.0480x over previous
//
#include <hip/hip_runtime.h>

#define DET 1024
#define CLIPV 20.0f

// DPP lane permutation (quad_perm imm8, 0x140 row_mirror, 0x141 row_half_mirror)
template<int CTRL>
__device__ __forceinline__ float dppx(float v) {
    int i = __float_as_int(v);
    int r = __builtin_amdgcn_update_dpp(i, i, CTRL, 0xF, 0xF, false);
    return __int_as_float(r);
}

struct Coef {
    float g10[6], g11[6], g20[6], g21[6];
    bool  j1[6];   // true iff t1 is the j=1 candidate (per lane, per phase)
};

// One ACS step at (wave-local) phase K. Verified butterfly algebra (rounds 3-17):
// lane L holds M_tau[rotr6(L, tau%6)]; partner = L^(1<<K).
template<int K, bool DEC>
__device__ __forceinline__ void acs_step(float lxv, float lyv, float& m, unsigned& acc,
                                         const Coef& cf) {
    float C1 = __builtin_fmaf(cf.g10[K], lxv, cf.g11[K] * lyv);
    float C2 = __builtin_fmaf(cf.g20[K], lxv, cf.g21[K] * lyv);
    float e1, e2;
    if constexpr (K == 0)      { e1 = m; e2 = dppx<0xB1>(m); }
    else if constexpr (K == 1) { e1 = m; e2 = dppx<0x4E>(m); }
    else if constexpr (K == 2) { e1 = m; e2 = dppx<0x141>(dppx<0x1B>(m)); }
    else if constexpr (K == 3) { e1 = m; e2 = dppx<0x140>(dppx<0x141>(m)); }
    else {
        int a1 = __float_as_int(m), a2;
        if constexpr (K == 4)
            asm("v_mov_b32 %1, %0\n\ts_nop 1\n\tv_permlane16_swap_b32 %0, %1\n\ts_nop 1"
                : "+v"(a1), "=&v"(a2));
        else
            asm("v_mov_b32 %1, %0\n\ts_nop 1\n\tv_permlane32_swap_b32 %0, %1\n\ts_nop 1"
                : "+v"(a1), "=&v"(a2));
        e1 = __int_as_float(a1); e2 = __int_as_float(a2);
    }
    float t1 = e1 + C1, t2 = e2 + C2;
    float mn = fminf(t1, t2);
    if constexpr (DEC) {
        // d = argmin j (tie -> j=0): tj0 = the j=0 candidate; d = (mn < tj0)
        float tj0 = cf.j1[K] ? t2 : t1;
        acc = acc + acc + (mn < tj0 ? 1u : 0u);
    }
    m = __builtin_amdgcn_fmed3f(mn, -CLIPV, CLIPV);
}

// 16-step block, loads at top (r10/r11-verified). At 4 waves/SIMD, TLP hides
// the LDS latency — no register double-buffer (r17's spilled: 10MB scratch).
template<int P, bool DEC>
__device__ __forceinline__ void sub16(const float2* lq, int& lidx,
                                      float& m, unsigned& acc, const Coef& cf) {
    const float4* bp = reinterpret_cast<const float4*>(lq + lidx);  // 16-aligned lidx
    float4 v[8];
    #pragma unroll
    for (int j = 0; j < 8; ++j) v[j] = bp[j];
    #define SPAIR(JH)                                                          \
        acs_step<(P + 2 * (JH)) % 6, DEC>(v[JH].x, v[JH].y, m, acc, cf);       \
        acs_step<(P + 2 * (JH) + 1) % 6, DEC>(v[JH].z, v[JH].w, m, acc, cf);
    SPAIR(0) SPAIR(1) SPAIR(2) SPAIR(3) SPAIR(4) SPAIR(5) SPAIR(6) SPAIR(7)
    #undef SPAIR
    lidx = (lidx + 16) & (DET - 1);
}

// 8 traceback steps from prefetched qword buffer (verified rounds 5-17).
#define TBSTEPS(QARR, TBTOP, RT) do {                                          \
    _Pragma("unroll")                                                          \
    for (int j = 0; j < 8; ++j) {                                              \
        const int t = (TBTOP) - j;                                             \
        int r = (RT) - (j % 6); if (r < 0) r += 6;                             \
        int Lx = ((st << r) | (st >> (6 - r))) & 63;                           \
        int bit = (int)((QARR[j] >> Lx) & 1ull);                               \
        unsigned ob = (~(unsigned)st) & 1u;                                    \
        int ii = t - 1024;                                                     \
        acc |= ob << (ii & 31);                                                \
        if ((ii & 31) == 0) { bitsl[cw][L][(ii >> 5) & 3] = acc; acc = 0; }    \
        st = ((st << 1) | bit) & 63;                                           \
    }                                                                          \
} while (0)

// 512 blocks x 512 threads (8 waves; 2 blocks/CU -> 4 waves/SIMD). One batch
// per block. Periodic input + W=96 exact coalescence (verified r13/r15-r17;
// W=48 refuted r14). Wave w: 96 warmup + 128 decode steps for chunk
// t in [1024+128w, 1024+128(w+1)); (96+128) % 6 == 2 -> traceback rtop = 2.
// No barriers between forward, own-window transpose, and own-chunk traceback.
__global__ __launch_bounds__(512, 4) void cva_kernel(const float* __restrict__ x,
                                                     float* __restrict__ out) {
    const int bidx = blockIdx.x;
    const int tid  = threadIdx.x;
    const int L    = tid & 63;
    const int w    = tid >> 6;

    __shared__ float2 lx[DET];                  // 8 KB LLR pairs
    __shared__ unsigned decw[32 * 64];          // 8 KB per-lane decision words
    __shared__ unsigned long long masks[1024];  // 8 KB t-indexed decision masks
    __shared__ unsigned bitsl[8][64][4];        // 8 KB speculative bit strings
    __shared__ unsigned char gmap[8][64];       // chunk state maps

    const float2* __restrict__ xrow =
        reinterpret_cast<const float2*>(x + (size_t)bidx * 2048);
    for (int i = tid; i < DET; i += 512) lx[i] = xrow[i];
    __syncthreads();

    // ---- forward ACS: wave w decodes t in [1024+128w, 1024+128(w+1)) ----
    {
        // probe permlane swap orientation once (per-lane constant; verified r5-r17)
        bool P16, P32;
        {
            int p1 = L, p2;
            asm("v_mov_b32 %1, %0\n\ts_nop 1\n\tv_permlane16_swap_b32 %0, %1\n\ts_nop 1"
                : "+v"(p1), "=&v"(p2));
            P16 = (p1 == (L ^ 16));
            int q1 = L, q2;
            asm("v_mov_b32 %1, %0\n\ts_nop 1\n\tv_permlane32_swap_b32 %0, %1\n\ts_nop 1"
                : "+v"(q1), "=&v"(q2));
            P32 = (q1 == (L ^ 32));
        }
        Coef cf;
        #pragma unroll
        for (int k = 0; k < 6; ++k) {
            int r = (k + 1) % 6;
            int sn = ((L >> r) | (L << (6 - r))) & 63;   // rotr6(L, r)
            int b = (sn >> 5) & 1;
            int q0 = (sn << 1) & 63;
            int q1b = q0 | 1;
            int qo = b ? q1b : q0;                       // own candidate  (j=b)
            int qp = b ? q0 : q1b;                       // partner's      (j=1-b)
            float fo0 = (float)((b ^ (qo >> 5) ^ (qo >> 4) ^ (qo >> 3) ^ qo) & 1);
            float fo1 = (float)((b ^ (qo >> 4) ^ (qo >> 3) ^ (qo >> 1) ^ qo) & 1);
            float fp0 = (float)((b ^ (qp >> 5) ^ (qp >> 4) ^ (qp >> 3) ^ qp) & 1);
            float fp1 = (float)((b ^ (qp >> 4) ^ (qp >> 3) ^ (qp >> 1) ^ qp) & 1);
            bool P = (k == 4) ? P16 : ((k == 5) ? P32 : false);
            cf.g10[k] = P ? fp0 : fo0; cf.g11[k] = P ? fp1 : fo1;   // coeffs for e1
            cf.g20[k] = P ? fo0 : fp0; cf.g21[k] = P ? fo1 : fp1;   // coeffs for e2
            cf.j1[k] = ((b != 0) != P);                  // t1 is j=1 cand iff b^P
        }

        float m = 0.0f;
        unsigned acc = 0;
        int lidx = (928 + 128 * w) & (DET - 1);          // warmup start = t0 - 96
        // warmup: 6 sub16 = 96 steps, phases cycle {0,4,2}
        sub16<0, false>(lx, lidx, m, acc, cf);
        sub16<4, false>(lx, lidx, m, acc, cf);
        sub16<2, false>(lx, lidx, m, acc, cf);
        sub16<0, false>(lx, lidx, m, acc, cf);
        sub16<4, false>(lx, lidx, m, acc, cf);
        sub16<2, false>(lx, lidx, m, acc, cf);
        // decode: 4 windows of 32 steps; window word -> LDS (keeps regs lean)
        #pragma unroll
        for (int wd = 0; wd < 4; ++wd) {
            const int ph = wd % 3;                       // window start phase (2*wd)%6
            if (ph == 0) {
                sub16<0, true>(lx, lidx, m, acc, cf);
                sub16<4, true>(lx, lidx, m, acc, cf);
            } else if (ph == 1) {
                sub16<2, true>(lx, lidx, m, acc, cf);
                sub16<0, true>(lx, lidx, m, acc, cf);
            } else {
                sub16<4, true>(lx, lidx, m, acc, cf);
                sub16<2, true>(lx, lidx, m, acc, cf);
            }
            decw[(4 * w + wd) * 64 + L] = acc;           // window index 4w+wd
        }
    }

    // ---- own-window bit-transpose (same-wave LDS readback, no barrier) ----
    for (int n = 0; n < 4; ++n) {
        unsigned W = decw[(4 * w + n) * 64 + L];
        unsigned mlo = 0, mhi = 0;
        #pragma unroll
        for (int i = 0; i < 32; ++i) {
            unsigned long long bal = __ballot(((W >> (31 - i)) & 1u) != 0);
            bool sel = (L == i);                         // lane i keeps t = 1024+(4w+n)*32+i
            mlo = sel ? (unsigned)bal : mlo;
            mhi = sel ? (unsigned)(bal >> 32) : mhi;
        }
        if (L < 32)
            masks[(4 * w + n) * 32 + L] = ((unsigned long long)mhi << 32) | mlo;
    }

    // ---- speculative traceback: chunk cw = w reads ONLY its own masks slice ----
    {
        const int cw = w;
        int st = L;                                      // speculative top-boundary state
        unsigned acc = 0;
        int tb0 = 1024 + 128 * cw + 127;
        int rtop = 2;                                    // (223+1)%6, same for all chunks
        unsigned long long qa[8], qb[8];
        #pragma unroll
        for (int j = 0; j < 8; ++j) qa[j] = masks[tb0 - 1024 - j];
        for (int blk = 0; blk < 16; blk += 2) {
            const int tb1 = tb0 - 8;
            #pragma unroll
            for (int j = 0; j < 8; ++j) qb[j] = masks[tb1 - 1024 - j];
            TBSTEPS(qa, tb0, rtop);
            const int tb2 = tb0 - 16;
            if (blk + 2 < 16) {
                #pragma unroll
                for (int j = 0; j < 8; ++j) qa[j] = masks[tb2 - 1024 - j];
            }
            int rt1 = rtop - 2; if (rt1 < 0) rt1 += 6;
            TBSTEPS(qb, tb1, rt1);
            rtop = rt1 - 2; if (rtop < 0) rtop += 6;
            tb0 -= 16;
        }
        gmap[cw][L] = (unsigned char)st;
    }
    __syncthreads();                                     // the ONLY tail barrier

    // ---- redundant per-thread compose (pass A = rep2 via periodicity, then
    //      emitting-pass entries, all statically unrolled) + direct output ----
    {
        int s = 0;                                       // state at t=3072 boundary
        s = gmap[7][s]; s = gmap[6][s]; s = gmap[5][s]; s = gmap[4][s];
        s = gmap[3][s]; s = gmap[2][s]; s = gmap[1][s]; s = gmap[0][s];  // pass A
        int e7 = s; s = gmap[7][s];
        int e6 = s; s = gmap[6][s];
        int e5 = s; s = gmap[5][s];
        int e4 = s; s = gmap[4][s];
        int e3 = s; s = gmap[3][s];
        int e2 = s; s = gmap[2][s];
        int e1 = s; s = gmap[1][s];
        int e0 = s;
        float* orow = out + (size_t)bidx * DET;
        const int word = (tid & 127) >> 5, bit = tid & 31;
        const int b = tid >> 7;                          // 0..3
        // element i = tid: chunk = b, entry selected statically
        int elo = (b & 1) ? e1 : e0;
        int ehi = (b & 1) ? e3 : e2;
        int ee  = (b & 2) ? ehi : elo;
        orow[tid] = (float)((bitsl[b][ee][word] >> bit) & 1u);
        // element i = 512 + tid: chunk = 4 + b
        int flo = (b & 1) ? e5 : e4;
        int fhi = (b & 1) ? e7 : e6;
        int ff  = (b & 2) ? fhi : flo;
        orow[tid + 512] = (float)((bitsl[4 + b][ff][word] >> bit) & 1u);
    }
}

extern "C" void kernel_launch(void* const* d_in, const int* in_sizes, int n_in,
                              void* d_out, int out_size, void* d_ws, size_t ws_size,
                              hipStream_t stream) {
    const float* x = (const float*)d_in[0];
    float* out = (float*)d_out;
    (void)in_sizes; (void)n_in; (void)d_ws; (void)ws_size; (void)out_size;
    hipLaunchKernelGGL(cva_kernel, dim3(512), dim3(512), 0, stream, x, out);
}

// Round 19
// 40.286 us; speedup vs baseline: 1.0924x; 1.0424x over previous
//
#include <hip/hip_runtime.h>

#define DET 1024
#define CLIPV 20.0f

// DPP lane permutation (quad_perm imm8, 0x140 row_mirror, 0x141 row_half_mirror)
template<int CTRL>
__device__ __forceinline__ float dppx(float v) {
    int i = __float_as_int(v);
    int r = __builtin_amdgcn_update_dpp(i, i, CTRL, 0xF, 0xF, false);
    return __int_as_float(r);
}

struct Coef {
    float g10[6], g11[6], g20[6], g21[6];
    bool  j1[6];   // true iff t1 is the j=1 candidate (per lane, per phase)
};

// One ACS step at (wave-local) phase K. Verified butterfly algebra (rounds 3-18):
// lane L holds M_tau[rotr6(L, tau%6)]; partner = L^(1<<K).
template<int K, bool DEC>
__device__ __forceinline__ void acs_step(float lxv, float lyv, float& m, unsigned& acc,
                                         const Coef& cf) {
    float C1 = __builtin_fmaf(cf.g10[K], lxv, cf.g11[K] * lyv);
    float C2 = __builtin_fmaf(cf.g20[K], lxv, cf.g21[K] * lyv);
    float e1, e2;
    if constexpr (K == 0)      { e1 = m; e2 = dppx<0xB1>(m); }
    else if constexpr (K == 1) { e1 = m; e2 = dppx<0x4E>(m); }
    else if constexpr (K == 2) { e1 = m; e2 = dppx<0x141>(dppx<0x1B>(m)); }
    else if constexpr (K == 3) { e1 = m; e2 = dppx<0x140>(dppx<0x141>(m)); }
    else {
        int a1 = __float_as_int(m), a2;
        if constexpr (K == 4)
            asm("v_mov_b32 %1, %0\n\ts_nop 1\n\tv_permlane16_swap_b32 %0, %1\n\ts_nop 1"
                : "+v"(a1), "=&v"(a2));
        else
            asm("v_mov_b32 %1, %0\n\ts_nop 1\n\tv_permlane32_swap_b32 %0, %1\n\ts_nop 1"
                : "+v"(a1), "=&v"(a2));
        e1 = __int_as_float(a1); e2 = __int_as_float(a2);
    }
    float t1 = e1 + C1, t2 = e2 + C2;
    float mn = fminf(t1, t2);
    if constexpr (DEC) {
        // d = argmin j (tie -> j=0): tj0 = the j=0 candidate; d = (mn < tj0)
        float tj0 = cf.j1[K] ? t2 : t1;
        acc = acc + acc + (mn < tj0 ? 1u : 0u);
    }
    m = __builtin_amdgcn_fmed3f(mn, -CLIPV, CLIPV);
}

// 16-step block, loads at top (r10/r11/r18-verified). At 4 waves/SIMD, TLP
// hides the LDS latency — no register double-buffer (r17's spilled).
template<int P, bool DEC>
__device__ __forceinline__ void sub16(const float2* lq, int& lidx,
                                      float& m, unsigned& acc, const Coef& cf) {
    const float4* bp = reinterpret_cast<const float4*>(lq + lidx);  // 16-aligned lidx
    float4 v[8];
    #pragma unroll
    for (int j = 0; j < 8; ++j) v[j] = bp[j];
    #define SPAIR(JH)                                                          \
        acs_step<(P + 2 * (JH)) % 6, DEC>(v[JH].x, v[JH].y, m, acc, cf);       \
        acs_step<(P + 2 * (JH) + 1) % 6, DEC>(v[JH].z, v[JH].w, m, acc, cf);
    SPAIR(0) SPAIR(1) SPAIR(2) SPAIR(3) SPAIR(4) SPAIR(5) SPAIR(6) SPAIR(7)
    #undef SPAIR
    lidx = (lidx + 16) & (DET - 1);
}

// 8 traceback steps from prefetched qword buffer (verified rounds 5-18).
#define TBSTEPS(QARR, TBTOP, RT) do {                                          \
    _Pragma("unroll")                                                          \
    for (int j = 0; j < 8; ++j) {                                              \
        const int t = (TBTOP) - j;                                             \
        int r = (RT) - (j % 6); if (r < 0) r += 6;                             \
        int Lx = ((st << r) | (st >> (6 - r))) & 63;                           \
        int bit = (int)((QARR[j] >> Lx) & 1ull);                               \
        unsigned ob = (~(unsigned)st) & 1u;                                    \
        int ii = t - 1024;                                                     \
        acc |= ob << (ii & 31);                                                \
        if ((ii & 31) == 0) { bitsl[cw][L][(ii >> 5) & 3] = acc; acc = 0; }    \
        st = ((st << 1) | bit) & 63;                                           \
    }                                                                          \
} while (0)

// 512 blocks x 512 threads (8 waves; 2 blocks/CU -> 4 waves/SIMD). One batch
// per block. Periodic input + clip-driven exact coalescence. Warmup W=64
// (bracket: 96 verified r13/r15-r18, 48 refuted r14; this round probes 64 —
// PRE-COMMIT: absmax=1.0 => W floor in (64,96], revert to 96). Wave w:
// 64 warmup + 128 decode for chunk t in [1024+128w, 1024+128(w+1));
// per-wave steps 192 -> 192 % 6 == 0 -> traceback rtop = 0.
// No barriers between forward, own-window transpose, own-chunk traceback.
__global__ __launch_bounds__(512, 4) void cva_kernel(const float* __restrict__ x,
                                                     float* __restrict__ out) {
    const int bidx = blockIdx.x;
    const int tid  = threadIdx.x;
    const int L    = tid & 63;
    const int w    = tid >> 6;

    __shared__ float2 lx[DET];                  // 8 KB LLR pairs
    __shared__ unsigned decw[32 * 64];          // 8 KB per-lane decision words
    __shared__ unsigned long long masks[1024];  // 8 KB t-indexed decision masks
    __shared__ unsigned bitsl[8][64][4];        // 8 KB speculative bit strings
    __shared__ unsigned char gmap[8][64];       // chunk state maps

    const float2* __restrict__ xrow =
        reinterpret_cast<const float2*>(x + (size_t)bidx * 2048);
    for (int i = tid; i < DET; i += 512) lx[i] = xrow[i];
    __syncthreads();

    // ---- forward ACS: wave w decodes t in [1024+128w, 1024+128(w+1)) ----
    {
        // probe permlane swap orientation once (per-lane constant; verified r5-r18)
        bool P16, P32;
        {
            int p1 = L, p2;
            asm("v_mov_b32 %1, %0\n\ts_nop 1\n\tv_permlane16_swap_b32 %0, %1\n\ts_nop 1"
                : "+v"(p1), "=&v"(p2));
            P16 = (p1 == (L ^ 16));
            int q1 = L, q2;
            asm("v_mov_b32 %1, %0\n\ts_nop 1\n\tv_permlane32_swap_b32 %0, %1\n\ts_nop 1"
                : "+v"(q1), "=&v"(q2));
            P32 = (q1 == (L ^ 32));
        }
        Coef cf;
        #pragma unroll
        for (int k = 0; k < 6; ++k) {
            int r = (k + 1) % 6;
            int sn = ((L >> r) | (L << (6 - r))) & 63;   // rotr6(L, r)
            int b = (sn >> 5) & 1;
            int q0 = (sn << 1) & 63;
            int q1b = q0 | 1;
            int qo = b ? q1b : q0;                       // own candidate  (j=b)
            int qp = b ? q0 : q1b;                       // partner's      (j=1-b)
            float fo0 = (float)((b ^ (qo >> 5) ^ (qo >> 4) ^ (qo >> 3) ^ qo) & 1);
            float fo1 = (float)((b ^ (qo >> 4) ^ (qo >> 3) ^ (qo >> 1) ^ qo) & 1);
            float fp0 = (float)((b ^ (qp >> 5) ^ (qp >> 4) ^ (qp >> 3) ^ qp) & 1);
            float fp1 = (float)((b ^ (qp >> 4) ^ (qp >> 3) ^ (qp >> 1) ^ qp) & 1);
            bool P = (k == 4) ? P16 : ((k == 5) ? P32 : false);
            cf.g10[k] = P ? fp0 : fo0; cf.g11[k] = P ? fp1 : fo1;   // coeffs for e1
            cf.g20[k] = P ? fo0 : fp0; cf.g21[k] = P ? fo1 : fp1;   // coeffs for e2
            cf.j1[k] = ((b != 0) != P);                  // t1 is j=1 cand iff b^P
        }

        float m = 0.0f;
        unsigned acc = 0;
        int lidx = (960 + 128 * w) & (DET - 1);          // warmup start = t0 - 64
        // warmup: 4 sub16 = 64 steps, phases 0,4,2,0 (advance 16%6=4 per sub16)
        sub16<0, false>(lx, lidx, m, acc, cf);
        sub16<4, false>(lx, lidx, m, acc, cf);
        sub16<2, false>(lx, lidx, m, acc, cf);
        sub16<0, false>(lx, lidx, m, acc, cf);
        // decode: 4 windows of 32 steps; start phases {4,0,2,4} = ((wd+2)%3 map)
        #pragma unroll
        for (int wd = 0; wd < 4; ++wd) {
            const int ph = (wd + 2) % 3;                 // {2,0,1,2} -> {(4,2),(0,4),(2,0),(4,2)}
            if (ph == 0) {
                sub16<0, true>(lx, lidx, m, acc, cf);
                sub16<4, true>(lx, lidx, m, acc, cf);
            } else if (ph == 1) {
                sub16<2, true>(lx, lidx, m, acc, cf);
                sub16<0, true>(lx, lidx, m, acc, cf);
            } else {
                sub16<4, true>(lx, lidx, m, acc, cf);
                sub16<2, true>(lx, lidx, m, acc, cf);
            }
            decw[(4 * w + wd) * 64 + L] = acc;           // window index 4w+wd
        }
    }

    // ---- own-window bit-transpose (same-wave LDS readback, no barrier) ----
    for (int n = 0; n < 4; ++n) {
        unsigned W = decw[(4 * w + n) * 64 + L];
        unsigned mlo = 0, mhi = 0;
        #pragma unroll
        for (int i = 0; i < 32; ++i) {
            unsigned long long bal = __ballot(((W >> (31 - i)) & 1u) != 0);
            bool sel = (L == i);                         // lane i keeps t = 1024+(4w+n)*32+i
            mlo = sel ? (unsigned)bal : mlo;
            mhi = sel ? (unsigned)(bal >> 32) : mhi;
        }
        if (L < 32)
            masks[(4 * w + n) * 32 + L] = ((unsigned long long)mhi << 32) | mlo;
    }

    // ---- speculative traceback: chunk cw = w reads ONLY its own masks slice ----
    {
        const int cw = w;
        int st = L;                                      // speculative top-boundary state
        unsigned acc = 0;
        int tb0 = 1024 + 128 * cw + 127;
        int rtop = 0;                                    // (191+1)%6, same for all chunks
        unsigned long long qa[8], qb[8];
        #pragma unroll
        for (int j = 0; j < 8; ++j) qa[j] = masks[tb0 - 1024 - j];
        for (int blk = 0; blk < 16; blk += 2) {
            const int tb1 = tb0 - 8;
            #pragma unroll
            for (int j = 0; j < 8; ++j) qb[j] = masks[tb1 - 1024 - j];
            TBSTEPS(qa, tb0, rtop);
            const int tb2 = tb0 - 16;
            if (blk + 2 < 16) {
                #pragma unroll
                for (int j = 0; j < 8; ++j) qa[j] = masks[tb2 - 1024 - j];
            }
            int rt1 = rtop - 2; if (rt1 < 0) rt1 += 6;
            TBSTEPS(qb, tb1, rt1);
            rtop = rt1 - 2; if (rtop < 0) rtop += 6;
            tb0 -= 16;
        }
        gmap[cw][L] = (unsigned char)st;
    }
    __syncthreads();                                     // the ONLY tail barrier

    // ---- redundant per-thread compose (pass A = rep2 via periodicity, then
    //      emitting-pass entries, all statically unrolled) + direct output ----
    {
        int s = 0;                                       // state at t=3072 boundary
        s = gmap[7][s]; s = gmap[6][s]; s = gmap[5][s]; s = gmap[4][s];
        s = gmap[3][s]; s = gmap[2][s]; s = gmap[1][s]; s = gmap[0][s];  // pass A
        int e7 = s; s = gmap[7][s];
        int e6 = s; s = gmap[6][s];
        int e5 = s; s = gmap[5][s];
        int e4 = s; s = gmap[4][s];
        int e3 = s; s = gmap[3][s];
        int e2 = s; s = gmap[2][s];
        int e1 = s; s = gmap[1][s];
        int e0 = s;
        float* orow = out + (size_t)bidx * DET;
        const int word = (tid & 127) >> 5, bit = tid & 31;
        const int b = tid >> 7;                          // 0..3
        // element i = tid: chunk = b, entry selected statically
        int elo = (b & 1) ? e1 : e0;
        int ehi = (b & 1) ? e3 : e2;
        int ee  = (b & 2) ? ehi : elo;
        orow[tid] = (float)((bitsl[b][ee][word] >> bit) & 1u);
        // element i = 512 + tid: chunk = 4 + b
        int flo = (b & 1) ? e5 : e4;
        int fhi = (b & 1) ? e7 : e6;
        int ff  = (b & 2) ? fhi : flo;
        orow[tid + 512] = (float)((bitsl[4 + b][ff][word] >> bit) & 1u);
    }
}

extern "C" void kernel_launch(void* const* d_in, const int* in_sizes, int n_in,
                              void* d_out, int out_size, void* d_ws, size_t ws_size,
                              hipStream_t stream) {
    const float* x = (const float*)d_in[0];
    float* out = (float*)d_out;
    (void)in_sizes; (void)n_in; (void)d_ws; (void)ws_size; (void)out_size;
    hipLaunchKernelGGL(cva_kernel, dim3(512), dim3(512), 0, stream, x, out);
}